// Round 1
// 344.167 us; speedup vs baseline: 1.0222x; 1.0222x over previous
//
#include <hip/hip_runtime.h>

constexpr int NZ   = 300, NX = 500, NPAD = 40;
constexpr int NZP  = NZ + NPAD;          // 340
constexpr int NXP  = NX + 2 * NPAD;      // 580 (divisible by 4)
constexpr int Bdim = 2, Cdim = 8;
constexpr int HW   = NZP * NXP;          // 197200
constexpr int S    = Bdim * Cdim * HW;   // 3155200
constexpr int NQ   = NXP / 4;            // 145 quads per row
constexpr int TQ   = Bdim * Cdim * NZP * NQ;  // 788800 total quads
constexpr float DT = 1e-3f;
constexpr float A2 = (float)((1.0 / 24.0) / 10.0);   // a/DX
constexpr float B2 = (float)((9.0 / 8.0) / 10.0);    // b/DX
constexpr float COEF = 0.43173470493638357f;         // -ln(1e-5)*3*4000/(2*(DX*NPAD)^2)

typedef float4 f4;

__device__ __forceinline__ f4 ld4(const float* p) { return *reinterpret_cast<const f4*>(p); }
__device__ __forceinline__ void st4(float* p, f4 v) { *reinterpret_cast<f4*>(p) = v; }
__device__ __forceinline__ void unp(float* w, f4 v) { w[0]=v.x; w[1]=v.y; w[2]=v.z; w[3]=v.w; }
__device__ __forceinline__ f4 mk4(const float* a) { return f4{a[0], a[1], a[2], a[3]}; }

__device__ __forceinline__ float dax_of(int j) {
    float ax = 1.0f;
    if (j < NPAD)                { int r = NPAD - 1 - j;      ax = COEF * (float)(r * r); }
    else if (j >= NX + NPAD)     { int r = j - (NX + NPAD);   ax = COEF * (float)(r * r); }
    return 1.0f - DT * ax;
}
__device__ __forceinline__ float daz_of(int i) {
    float az = 1.0f;
    if (i >= NZ)                 { int r = i - NZ;            az = COEF * (float)(r * r); }
    return 1.0f - DT * az;
}

// ---------------- Kernel 1: velocity update (PML split), 4 pts/thread ----------------
__global__ __launch_bounds__(256) void k_vel(
    const float* __restrict__ txx, const float* __restrict__ tzz, const float* __restrict__ txz,
    const float* __restrict__ vx_x, const float* __restrict__ vx_z,
    const float* __restrict__ vz_x, const float* __restrict__ vz_z,
    const float* __restrict__ rho,
    const float* __restrict__ fs, const int* __restrict__ zs, const int* __restrict__ xs,
    float* __restrict__ out)
{
    int Q = blockIdx.x * 256 + threadIdx.x;
    if (Q >= TQ) return;
    int q  = Q % NQ;
    int t  = Q / NQ;
    int i  = t % NZP;
    int bc = t / NZP;
    int c  = bc % Cdim;
    int b  = bc / Cdim;
    int j0 = q * 4;
    int p  = i * NXP + j0;
    long gidx = (long)bc * HW + p;

    const bool hasL  = (q > 0),        hasR  = (q < NQ - 1);
    const bool hasU1 = (i >= 1),       hasU2 = (i >= 2);
    const bool hasD1 = (i + 1 < NZP),  hasD2 = (i + 2 < NZP);
    const f4 z4 = {0.f, 0.f, 0.f, 0.f};

    const float* TXX = txx + (long)bc * HW;
    const float* TZZ = tzz + (long)bc * HW;
    const float* TXZ = txz + (long)bc * HW;

    // txx: x-window only (KX) -> 12-float window j0-4 .. j0+7
    float wxx[12];
    unp(wxx,     hasL ? ld4(TXX + p - 4) : z4);
    unp(wxx + 4, ld4(TXX + p));
    unp(wxx + 8, hasR ? ld4(TXX + p + 4) : z4);

    // txz: x-window (KXU) + z-window (KZU)
    float wxz[12];
    unp(wxz,     hasL ? ld4(TXZ + p - 4) : z4);
    unp(wxz + 4, ld4(TXZ + p));
    unp(wxz + 8, hasR ? ld4(TXZ + p + 4) : z4);
    float zu2[4], zu1[4], zd1[4];
    unp(zu2, hasU2 ? ld4(TXZ + p - 2 * NXP) : z4);
    unp(zu1, hasU1 ? ld4(TXZ + p - NXP)     : z4);
    unp(zd1, hasD1 ? ld4(TXZ + p + NXP)     : z4);

    // tzz: z-window only (KZ), with point-source injection
    float tu1[4], t0[4], td1[4], td2[4];
    unp(tu1, hasU1 ? ld4(TZZ + p - NXP)     : z4);
    unp(t0,  ld4(TZZ + p));
    unp(td1, hasD1 ? ld4(TZZ + p + NXP)     : z4);
    unp(td2, hasD2 ? ld4(TZZ + p + 2 * NXP) : z4);
    {
        int sz  = zs[c];
        int sxp = xs[c] + NPAD;
        int e   = sxp - j0;
        if (e >= 0 && e < 4) {
            float fsb = fs[b];
            #pragma unroll
            for (int k = 0; k < 4; ++k) if (k == e) {   // static indices only (no scratch)
                if (i - 1 == sz) tu1[k] += fsb;
                if (i     == sz) t0[k]  += fsb;
                if (i + 1 == sz) td1[k] += fsb;
                if (i + 2 == sz) td2[k] += fsb;
            }
        }
    }

    float rr[4];  unp(rr,  ld4(rho  + (long)b * HW + p));
    float pxx[4]; unp(pxx, ld4(vx_x + gidx));
    float pxz[4]; unp(pxz, ld4(vx_z + gidx));
    float pzx[4]; unp(pzx, ld4(vz_x + gidx));
    float pzz[4]; unp(pzz, ld4(vz_z + gidx));

    float daz = daz_of(i);
    float o_vx[4], o_vz[4], o_vxx[4], o_vxz[4], o_vzx[4], o_vzz[4];
    #pragma unroll
    for (int e = 0; e < 4; ++e) {
        float rinv = 1.0f / rr[e];
        float var_txx_x = (A2 * (wxx[3 + e] - wxx[6 + e]) + B2 * (wxx[5 + e] - wxx[4 + e])) * rinv; // KX
        float var_txz_x = (A2 * (wxz[2 + e] - wxz[5 + e]) + B2 * (wxz[4 + e] - wxz[3 + e])) * rinv; // KXU
        float var_txz_z = (A2 * (zu2[e]     - zd1[e])     + B2 * (wxz[4 + e] - zu1[e]))     * rinv; // KZU
        float var_tzz_z = (A2 * (tu1[e]     - td2[e])     + B2 * (td1[e]     - t0[e]))      * rinv; // KZ
        float dax = dax_of(j0 + e);
        float nvx_x = dax * pxx[e] + DT * var_txx_x;
        float nvx_z = daz * pxz[e] + DT * var_txz_z;
        float nvz_x = dax * pzx[e] + DT * var_txz_x;
        float nvz_z = daz * pzz[e] + DT * var_tzz_z;
        o_vxx[e] = nvx_x; o_vxz[e] = nvx_z; o_vzx[e] = nvz_x; o_vzz[e] = nvz_z;
        o_vx[e] = nvx_x + nvx_z; o_vz[e] = nvz_x + nvz_z;
    }

    st4(out + 0 * (long)S + gidx, mk4(o_vx));
    st4(out + 1 * (long)S + gidx, mk4(o_vz));
    st4(out + 5 * (long)S + gidx, mk4(o_vxx));
    st4(out + 6 * (long)S + gidx, mk4(o_vxz));
    st4(out + 7 * (long)S + gidx, mk4(o_vzx));
    st4(out + 8 * (long)S + gidx, mk4(o_vzz));
}

// ---------------- Kernel 2: stress update (PML split), 4 pts/thread ----------------
__global__ __launch_bounds__(256) void k_stress(
    const float* __restrict__ txx_x, const float* __restrict__ txx_z,
    const float* __restrict__ tzz_x, const float* __restrict__ tzz_z,
    const float* __restrict__ txz_x, const float* __restrict__ txz_z,
    const float* __restrict__ vp, const float* __restrict__ vs, const float* __restrict__ rho,
    float* __restrict__ out)
{
    int Q = blockIdx.x * 256 + threadIdx.x;
    if (Q >= TQ) return;
    int q  = Q % NQ;
    int t  = Q / NQ;
    int i  = t % NZP;
    int bc = t / NZP;
    int b  = bc / Cdim;
    int j0 = q * 4;
    int p  = i * NXP + j0;
    long gidx = (long)bc * HW + p;

    const bool hasL  = (q > 0),        hasR  = (q < NQ - 1);
    const bool hasU1 = (i >= 1),       hasU2 = (i >= 2);
    const bool hasD1 = (i + 1 < NZP),  hasD2 = (i + 2 < NZP);
    const f4 z4 = {0.f, 0.f, 0.f, 0.f};

    const float* VX = out + 0 * (long)S + (long)bc * HW;
    const float* VZ = out + 1 * (long)S + (long)bc * HW;

    // vx: x-window (KXU) + z-window (KZ)
    float wx[12];
    unp(wx,     hasL ? ld4(VX + p - 4) : z4);
    unp(wx + 4, ld4(VX + p));
    unp(wx + 8, hasR ? ld4(VX + p + 4) : z4);
    float xu1[4], xd1[4], xd2[4];
    unp(xu1, hasU1 ? ld4(VX + p - NXP)     : z4);
    unp(xd1, hasD1 ? ld4(VX + p + NXP)     : z4);
    unp(xd2, hasD2 ? ld4(VX + p + 2 * NXP) : z4);

    // vz: x-window (KX) + z-window (KZU)
    float wz[12];
    unp(wz,     hasL ? ld4(VZ + p - 4) : z4);
    unp(wz + 4, ld4(VZ + p));
    unp(wz + 8, hasR ? ld4(VZ + p + 4) : z4);
    float zu2[4], zu1[4], zd1[4];
    unp(zu2, hasU2 ? ld4(VZ + p - 2 * NXP) : z4);
    unp(zu1, hasU1 ? ld4(VZ + p - NXP)     : z4);
    unp(zd1, hasD1 ? ld4(VZ + p + NXP)     : z4);

    long mp = (long)b * HW + p;
    float vpv[4], vsv[4], rh[4];
    unp(vpv, ld4(vp + mp));
    unp(vsv, ld4(vs + mp));
    unp(rh,  ld4(rho + mp));

    float pxxx[4], pxxz[4], pzzx[4], pzzz[4], pxzx[4], pxzz[4];
    unp(pxxx, ld4(txx_x + gidx));
    unp(pxxz, ld4(txx_z + gidx));
    unp(pzzx, ld4(tzz_x + gidx));
    unp(pzzz, ld4(tzz_z + gidx));
    unp(pxzx, ld4(txz_x + gidx));
    unp(pxzz, ld4(txz_z + gidx));

    float daz = daz_of(i);
    float o_txx[4], o_tzz[4], o_txz[4];
    float o_xxx[4], o_xxz[4], o_zzx[4], o_zzz[4], o_xzx[4], o_xzz[4];
    #pragma unroll
    for (int e = 0; e < 4; ++e) {
        float var_vx_x = A2 * (wx[2 + e] - wx[5 + e]) + B2 * (wx[4 + e] - wx[3 + e]); // KXU
        float var_vx_z = A2 * (xu1[e]    - xd2[e])    + B2 * (xd1[e]    - wx[4 + e]); // KZ
        float var_vz_x = A2 * (wz[3 + e] - wz[6 + e]) + B2 * (wz[5 + e] - wz[4 + e]); // KX
        float var_vz_z = A2 * (zu2[e]    - zd1[e])    + B2 * (wz[4 + e] - zu1[e]);    // KZU

        float lam2mu = vpv[e] * vpv[e] * rh[e];
        float mu     = vsv[e] * vsv[e] * rh[e];
        float lam    = lam2mu - 2.0f * mu;
        float dax = dax_of(j0 + e);

        float ntxx_x = dax * pxxx[e] + DT * lam2mu * var_vx_x;
        float ntxx_z = daz * pxxz[e] + DT * lam    * var_vz_z;
        float ntzz_x = dax * pzzx[e] + DT * lam    * var_vx_x;
        float ntzz_z = daz * pzzz[e] + DT * lam2mu * var_vz_z;
        float ntxz_x = dax * pxzx[e] + DT * mu     * var_vz_x;
        float ntxz_z = daz * pxzz[e] + DT * mu     * var_vx_z;

        o_txx[e] = ntxx_x + ntxx_z;
        o_tzz[e] = ntzz_x + ntzz_z;
        o_txz[e] = ntxz_x + ntxz_z;
        o_xxx[e] = ntxx_x; o_xxz[e] = ntxx_z;
        o_zzx[e] = ntzz_x; o_zzz[e] = ntzz_z;
        o_xzx[e] = ntxz_x; o_xzz[e] = ntxz_z;
    }

    st4(out +  2 * (long)S + gidx, mk4(o_txx));
    st4(out +  3 * (long)S + gidx, mk4(o_tzz));
    st4(out +  4 * (long)S + gidx, mk4(o_txz));
    st4(out +  9 * (long)S + gidx, mk4(o_xxx));
    st4(out + 10 * (long)S + gidx, mk4(o_xxz));
    st4(out + 11 * (long)S + gidx, mk4(o_zzx));
    st4(out + 12 * (long)S + gidx, mk4(o_zzz));
    st4(out + 13 * (long)S + gidx, mk4(o_xzx));
    st4(out + 14 * (long)S + gidx, mk4(o_xzz));
}

extern "C" void kernel_launch(void* const* d_in, const int* in_sizes, int n_in,
                              void* d_out, int out_size, void* d_ws, size_t ws_size,
                              hipStream_t stream) {
    const float* txx   = (const float*)d_in[0];
    const float* tzz   = (const float*)d_in[1];
    const float* txz   = (const float*)d_in[2];
    const float* vx_x  = (const float*)d_in[3];
    const float* vx_z  = (const float*)d_in[4];
    const float* vz_x  = (const float*)d_in[5];
    const float* vz_z  = (const float*)d_in[6];
    const float* txx_x = (const float*)d_in[7];
    const float* txx_z = (const float*)d_in[8];
    const float* tzz_x = (const float*)d_in[9];
    const float* tzz_z = (const float*)d_in[10];
    const float* txz_x = (const float*)d_in[11];
    const float* txz_z = (const float*)d_in[12];
    const float* vp    = (const float*)d_in[13];
    const float* vs    = (const float*)d_in[14];
    const float* rho   = (const float*)d_in[15];
    const float* fs    = (const float*)d_in[16];
    const int*   zs    = (const int*)d_in[17];
    const int*   xs    = (const int*)d_in[18];
    float* out = (float*)d_out;

    dim3 grid((TQ + 255) / 256), block(256);
    k_vel<<<grid, block, 0, stream>>>(txx, tzz, txz, vx_x, vx_z, vz_x, vz_z,
                                      rho, fs, zs, xs, out);
    k_stress<<<grid, block, 0, stream>>>(txx_x, txx_z, tzz_x, tzz_z, txz_x, txz_z,
                                         vp, vs, rho, out);
}